// Round 1
// 1163.524 us; speedup vs baseline: 1.0771x; 1.0771x over previous
//
#include <hip/hip_runtime.h>

// Problem constants
#define NUM_USERS 8192
#define NUM_ITEMS 32768
#define FEAT 129
#define KP 160            // K padded to multiple of 32 (5 MFMA k-steps)
#define NOUT 32768        // output row stride (= NUM_ITEMS)

typedef _Float16 f16x8 __attribute__((ext_vector_type(8)));
typedef float    f32x4 __attribute__((ext_vector_type(4)));

// ---------------------------------------------------------------------------
// Pack: h (40960 x 129 fp32) -> A (8192 x 160 fp16, col0 negated), B (32768 x 160 fp16)
// Zero-pad cols [129,160). Re-written every launch (ws is re-poisoned).
// ---------------------------------------------------------------------------
__global__ void pack_kernel(const float* __restrict__ h,
                            _Float16* __restrict__ apack,
                            _Float16* __restrict__ bpack) {
    int idx = blockIdx.x * blockDim.x + threadIdx.x;   // 0 .. 40960*160-1
    int row = idx / KP;
    int col = idx - row * KP;
    float v = 0.0f;
    if (col < FEAT) v = h[(size_t)row * FEAT + col];
    if (row < NUM_USERS) {
        if (col == 0) v = -v;                           // signs[0] = -1 folded into A
        apack[(size_t)row * KP + col] = (_Float16)v;
    } else {
        bpack[(size_t)(row - NUM_USERS) * KP + col] = (_Float16)v;
    }
}

// ---------------------------------------------------------------------------
// GEMM + arccosh^2 epilogue. 128x128 tile per block (256 threads = 4 waves,
// each wave a 64x64 subtile = 4x4 MFMA 16x16x32_f16 fragments).
//
// v2 changes vs m97-structure baseline:
//  - ONE-SHOT staging: K=160 fits entirely in LDS (5 slabs of [128][32] halves
//    per operand = 40 KB each, 80 KB total). 20 global_load_lds per thread,
//    a single vmcnt(0)+barrier, then a barrier-free MFMA run. Removes the
//    10 per-K-step barrier drains.
//  - SWAPPED MFMA operands: acc = mfma(bf, af, acc). Fragment layouts are
//    symmetric, so D's row=(lane>>4)*4+reg now indexes n and col=lane&15
//    indexes m -> each f32x4 acc quad holds 4 CONSECUTIVE n at fixed m ->
//    epilogue stores become 16 global_store_dwordx4 (nontemporal) instead of
//    64 scalar dwords.
//  - XCD-aware bijective swizzle: xcd = bid&7 owns a 32-tile N-slice.
//    Per-XCD L2 working set = B-slice (1.31 MB) + current A-tile (40 KB),
//    fully L2-resident; A-tile reused 32x back-to-back.
// ---------------------------------------------------------------------------
__global__ __launch_bounds__(256, 2) void gemm_arccosh_kernel(
        const _Float16* __restrict__ A,   // M x KP, row-major
        const _Float16* __restrict__ B,   // N x KP, row-major (B^T form)
        float* __restrict__ out) {        // M x N
    // 5 K-slabs of [128 rows][32 halves] = 8192 B each; 40960 B per operand.
    __shared__ __align__(16) _Float16 As[5 * 128 * 32];   // 40 KB
    __shared__ __align__(16) _Float16 Bs[5 * 128 * 32];   // 40 KB

    const int t  = threadIdx.x;
    const int l  = t & 63;
    const int w  = t >> 6;
    const int wm = (w >> 1) * 64;     // wave row offset in tile (m)
    const int wn = (w & 1)  * 64;     // wave col offset in tile (n)
    const int q  = l >> 4;            // quad id 0..3
    const int lm = l & 15;

    // XCD swizzle: consecutive blockIdx round-robin across 8 XCDs (m09), so
    // bid&7 = xcd. Each XCD owns N-tiles [xcd*32, xcd*32+32); within an XCD,
    // walk x fast (A-tile reuse), y slow. Bijective: bid = y*256 + xloc*8 + xcd.
    const int bid = blockIdx.x;
    const int seq = bid >> 3;
    const int nBase = (((bid & 7) << 5) + (seq & 31)) << 7;   // x-tile * 128
    const int mBase = (seq >> 5) << 7;                        // y-tile * 128

    // ---- one-shot staging: whole K strip for both tiles ----
    // Byte offset ob in [0, 40960): slab ks = ob>>13, within-slab row-major
    // [128][64B]. LDS dest is wave-uniform base + lane*16 (linear) as required.
    // Per-slab layout matches the verified conflict-free fragment-read pattern.
#pragma unroll
    for (int i = 0; i < 10; i++) {
        const int ob   = i * 4096 + t * 16;    // byte offset in 40 KB tile
        const int ks   = ob >> 13;             // k-slab 0..4
        const int orem = ob & 8191;
        const int row  = orem >> 6;            // row 0..127
        const int kc   = (orem >> 4) & 3;      // 16B chunk in 64B row
        const int koff = ks * 32 + kc * 8;     // halves offset in K
        const _Float16* ga = A + (size_t)(mBase + row) * KP + koff;
        __builtin_amdgcn_global_load_lds(
            (const __attribute__((address_space(1))) unsigned int*)ga,
            (__attribute__((address_space(3))) unsigned int*)((char*)As + ob),
            16, 0, 0);
        const _Float16* gb = B + (size_t)(nBase + row) * KP + koff;
        __builtin_amdgcn_global_load_lds(
            (const __attribute__((address_space(1))) unsigned int*)gb,
            (__attribute__((address_space(3))) unsigned int*)((char*)Bs + ob),
            16, 0, 0);
    }
    __syncthreads();   // single vmcnt(0) drain for the whole kernel

    f32x4 acc[4][4];
#pragma unroll
    for (int i = 0; i < 4; i++)
#pragma unroll
        for (int j = 0; j < 4; j++) acc[i][j] = (f32x4){0.f, 0.f, 0.f, 0.f};

    // ---- barrier-free MFMA run over 5 k-slabs ----
#pragma unroll
    for (int ks = 0; ks < 5; ks++) {
        f16x8 af[4], bf[4];
#pragma unroll
        for (int im = 0; im < 4; im++)
            af[im] = *(const f16x8*)&As[ks * 4096 + (wm + im * 16 + lm) * 32 + q * 8];
#pragma unroll
        for (int in = 0; in < 4; in++)
            bf[in] = *(const f16x8*)&Bs[ks * 4096 + (wn + in * 16 + lm) * 32 + q * 8];
#pragma unroll
        for (int im = 0; im < 4; im++)
#pragma unroll
            for (int in = 0; in < 4; in++)
                acc[im][in] = __builtin_amdgcn_mfma_f32_16x16x32_f16(
                    bf[in], af[im], acc[im][in], 0, 0, 0);   // SWAPPED operands
    }

    // ---- epilogue ----
    // Swapped layout: value at (m = mBase+wm+im*16+lm, n = nBase+wn+in*16+q*4+r)
    // = acc[im][in][r]. The 4 regs are 4 consecutive n -> dwordx4 store.
    // sqdist = min(arccosh(max(-prod, 1+eps))^2, 50); out = -sqdist
    //        = max(-ac*ac, -50).
#pragma unroll
    for (int im = 0; im < 4; im++) {
        float* orow = out + (size_t)(mBase + wm + im * 16 + lm) * NOUT;
#pragma unroll
        for (int in = 0; in < 4; in++) {
            f32x4 v;
#pragma unroll
            for (int r = 0; r < 4; r++) {
                const float prod  = acc[im][in][r];
                const float theta = fmaxf(-prod, 1.0f + 1e-7f);
                const float t2    = fmaxf(__builtin_fmaf(theta, theta, -1.0f), 0.0f);
                const float ac    = __logf(theta + __builtin_sqrtf(t2));
                v[r] = fmaxf(-(ac * ac), -50.0f);
            }
            __builtin_nontemporal_store(
                v, (f32x4*)(orow + (nBase + wn + in * 16 + q * 4)));
        }
    }
}

extern "C" void kernel_launch(void* const* d_in, const int* in_sizes, int n_in,
                              void* d_out, int out_size, void* d_ws, size_t ws_size,
                              hipStream_t stream) {
    const float* h = (const float*)d_in[0];
    float* out = (float*)d_out;

    _Float16* apack = (_Float16*)d_ws;                       // 8192*160*2  = 2.62 MB
    _Float16* bpack = apack + (size_t)NUM_USERS * KP;        // 32768*160*2 = 10.49 MB

    const int total = (NUM_USERS + NUM_ITEMS) * KP;          // 6,553,600 (exact /256)
    pack_kernel<<<total / 256, 256, 0, stream>>>(h, apack, bpack);

    const int nblocks = (NUM_ITEMS / 128) * (NUM_USERS / 128);   // 16384
    gemm_arccosh_kernel<<<nblocks, 256, 0, stream>>>(apack, bpack, out);
}